// Round 1
// 420.973 us; speedup vs baseline: 1.0315x; 1.0315x over previous
//
#include <hip/hip_runtime.h>
#include <hip/hip_bf16.h>

#define NN 4096      // nodes
#define ED 1024      // edim
#define WF 1024      // wfeat
#define SLOPEC 0.01f
#define NEG_INFC -1e9f

typedef __attribute__((ext_vector_type(8))) short bf16x8;
typedef __attribute__((ext_vector_type(4))) short short4v;
typedef __attribute__((ext_vector_type(4))) float f32x4;
typedef __attribute__((ext_vector_type(4))) int int4v;

__device__ __forceinline__ float bf2f(short s) {
    union { unsigned u; float f; } v;
    v.u = ((unsigned)(unsigned short)s) << 16;
    return v.f;
}
__device__ __forceinline__ short f2bf(float f) {
    unsigned u = __float_as_uint(f);
    unsigned r = u + 0x7FFFu + ((u >> 16) & 1u);   // RNE (finite data)
    return (short)(r >> 16);
}

typedef __attribute__((address_space(3))) unsigned lds_u32;
typedef const __attribute__((address_space(1))) unsigned gbl_u32;
__device__ __forceinline__ void g2l16(const short* g, short* l) {
    __builtin_amdgcn_global_load_lds((gbl_u32*)g, (lds_u32*)l, 16, 0, 0);
}

// ---------------------------------------------------------------------------
// Fused prep:
//  blocks [0,256): transpose+convert W [ED][WF] fp32 -> Wt [WF][ED] bf16
//  blocks [256,256+NN): gather+convert X[i][k] = bf16(emb[inSen[i]][k])
// ---------------------------------------------------------------------------
__global__ __launch_bounds__(256) void k_prep(const float* __restrict__ W,
                                              short* __restrict__ Wt,
                                              const int* __restrict__ inSen,
                                              const float* __restrict__ emb,
                                              short* __restrict__ X) {
    if (blockIdx.x < 256) {
        __shared__ float t[64][65];
        const int n0 = (blockIdx.x & 15) * 64, k0 = (blockIdx.x >> 4) * 64;
        const int tx = threadIdx.x & 63, ty = threadIdx.x >> 6;
#pragma unroll
        for (int p = 0; p < 16; p++) {
            int r = p * 4 + ty;
            t[r][tx] = W[(long)(k0 + r) * WF + n0 + tx];
        }
        __syncthreads();
#pragma unroll
        for (int p = 0; p < 16; p++) {
            int r = p * 4 + ty;  // n index
            Wt[(long)(n0 + r) * ED + k0 + tx] = f2bf(t[tx][r]);
        }
    } else {
        const int row = blockIdx.x - 256;
        const int tid = threadIdx.x;
        const long idx = inSen[row];
        const float4 v = ((const float4*)(emb + idx * ED))[tid];
        short4v s;
        s.x = f2bf(v.x); s.y = f2bf(v.y); s.z = f2bf(v.z); s.w = f2bf(v.w);
        *(short4v*)(X + (long)row * ED + tid * 4) = s;
    }
}

// ---------------------------------------------------------------------------
// GEMM (m97 structure): C[M][N](+)= A[M][K] * Bt[N][K], bf16 in.
// Tile BM x BN, BK=32, 256 thr = 4 waves (2x2). global_load_lds width=16.
// MODE 0: bf16 C store via LDS repack + fused s_src/s_dst column scores.
// MODE 1: fp32 atomicAdd into C (split-K accumulate) + fused pool colsum.
// ---------------------------------------------------------------------------
template <int BM, int BN, int MODE>
__global__ __launch_bounds__(256, 2) void gemm_bt2(
    const short* __restrict__ A, const short* __restrict__ Bt,
    int N, int K, int Kc, void* __restrict__ Cout,
    const float* __restrict__ a_src, const float* __restrict__ a_dst,
    float* __restrict__ s_src, float* __restrict__ s_dst,
    float* __restrict__ pool) {
    constexpr int TM = BM / 32;           // m-frags per wave
    constexpr int TN = BN / 32;           // n-frags per wave
    constexpr int STAGE = BM * 32 + BN * 32;
    constexpr int SMEMSZ = (MODE == 0 && BM * BN > STAGE) ? BM * BN : STAGE;
    __shared__ __align__(16) short smem[SMEMSZ];
    short* sA = smem;
    short* sB = smem + BM * 32;

    const int tid = threadIdx.x;
    const int lane = tid & 63;
    const int wid = tid >> 6;
    const int wm = wid >> 1, wn = wid & 1;
    const int n0 = blockIdx.x * BN;
    const int m0 = blockIdx.y * BM;
    const int ks = blockIdx.z * Kc;

    const int srow = tid >> 2;        // 0..63
    const int sc8 = (tid & 3) * 8;    // 0,8,16,24
    const int l15 = lane & 15;
    const int lhi = lane >> 4;

    f32x4 acc[TM][TN];
#pragma unroll
    for (int t = 0; t < TM; t++)
#pragma unroll
        for (int u = 0; u < TN; u++) acc[t][u] = (f32x4){0.f, 0.f, 0.f, 0.f};

    const short* Ab = A + (long)(m0 + srow) * K + ks + sc8;
    const short* Bb = Bt + (long)(n0 + srow) * K + ks + sc8;
    const long rstep = (long)64 * K;   // 64 rows

    for (int k0 = 0; k0 < Kc; k0 += 32) {
#pragma unroll
        for (int p = 0; p < BM / 64; p++)
            g2l16(Ab + p * rstep + k0, sA + (p * 256 + wid * 64) * 8);
#pragma unroll
        for (int p = 0; p < BN / 64; p++)
            g2l16(Bb + p * rstep + k0, sB + (p * 256 + wid * 64) * 8);
        __syncthreads();   // drains vmcnt for global_load_lds

        bf16x8 af[TM], bfr[TN];
#pragma unroll
        for (int t = 0; t < TM; t++)
            af[t] = *(const bf16x8*)&sA[(wm * (BM / 2) + t * 16 + l15) * 32 + lhi * 8];
#pragma unroll
        for (int u = 0; u < TN; u++)
            bfr[u] = *(const bf16x8*)&sB[(wn * (BN / 2) + u * 16 + l15) * 32 + lhi * 8];
#pragma unroll
        for (int t = 0; t < TM; t++)
#pragma unroll
            for (int u = 0; u < TN; u++)
                acc[t][u] = __builtin_amdgcn_mfma_f32_16x16x32_bf16(
                    af[t], bfr[u], acc[t][u], 0, 0, 0);
        __syncthreads();
    }

    // Epilogue. D mapping per 16x16 tile: col = l15, row = lhi*4 + r
    if (MODE == 0) {
        short* sT = smem;   // safe: last loop iteration ended with a barrier
#pragma unroll
        for (int t = 0; t < TM; t++)
#pragma unroll
            for (int u = 0; u < TN; u++)
#pragma unroll
                for (int r = 0; r < 4; r++) {
                    int m = wm * (BM / 2) + t * 16 + lhi * 4 + r;
                    int n = wn * (BN / 2) + u * 16 + l15;
                    sT[m * BN + n] = f2bf(acc[t][u][r]);
                }
        __syncthreads();
        short* C = (short*)Cout;
#pragma unroll
        for (int q = 0; q < BM * BN / 2048; q++) {
            int idx = q * 256 + tid;
            int row = idx / (BN / 8);
            int c8 = (idx % (BN / 8)) * 8;
            *(bf16x8*)(C + (long)(m0 + row) * N + n0 + c8) =
                *(const bf16x8*)&sT[row * BN + c8];
        }
        // s_src[n] += sum_m Ht[m][n]*a_src[m] over this block's m-range
        float ps[TN], pd[TN];
#pragma unroll
        for (int u = 0; u < TN; u++) { ps[u] = 0.f; pd[u] = 0.f; }
#pragma unroll
        for (int t = 0; t < TM; t++)
#pragma unroll
            for (int r = 0; r < 4; r++) {
                int m = m0 + wm * (BM / 2) + t * 16 + lhi * 4 + r;
                float as = a_src[m], ad = a_dst[m];
#pragma unroll
                for (int u = 0; u < TN; u++) {
                    ps[u] += acc[t][u][r] * as;
                    pd[u] += acc[t][u][r] * ad;
                }
            }
#pragma unroll
        for (int u = 0; u < TN; u++) {
            ps[u] += __shfl_xor(ps[u], 16); ps[u] += __shfl_xor(ps[u], 32);
            pd[u] += __shfl_xor(pd[u], 16); pd[u] += __shfl_xor(pd[u], 32);
        }
        if (lane < 16) {
#pragma unroll
            for (int u = 0; u < TN; u++) {
                int n = n0 + wn * (BN / 2) + u * 16 + lane;
                atomicAdd(s_src + n, ps[u]);
                atomicAdd(s_dst + n, pd[u]);
            }
        }
    } else {
        // MODE 1: split-K accumulate straight into fp32 C (pre-zeroed) and
        // fuse pool colsum (pool[n] += sum_m C_partial[m][n]).
        float* C = (float*)Cout;
        float pp[TN];
#pragma unroll
        for (int u = 0; u < TN; u++) pp[u] = 0.f;
#pragma unroll
        for (int t = 0; t < TM; t++)
#pragma unroll
            for (int u = 0; u < TN; u++)
#pragma unroll
                for (int r = 0; r < 4; r++) {
                    int m = wm * (BM / 2) + t * 16 + lhi * 4 + r;
                    int n = wn * (BN / 2) + u * 16 + l15;
                    atomicAdd(C + (long)(m0 + m) * N + n0 + n, acc[t][u][r]);
                    pp[u] += acc[t][u][r];
                }
#pragma unroll
        for (int u = 0; u < TN; u++) {
            pp[u] += __shfl_xor(pp[u], 16);
            pp[u] += __shfl_xor(pp[u], 32);
        }
        if (lane < 16) {
#pragma unroll
            for (int u = 0; u < TN; u++) {
                int n = n0 + wn * (BN / 2) + u * 16 + lane;
                atomicAdd(pool + n, pp[u]);
            }
        }
    }
}

// ---------------------------------------------------------------------------
// Masked softmax row -> attn fp32 (d_out, NT) + attnB bf16 (ws, GEMM2 A)
// ---------------------------------------------------------------------------
__global__ __launch_bounds__(256) void k_attn(const int* __restrict__ adj,
                                              const float* __restrict__ s_src,
                                              const float* __restrict__ s_dst,
                                              float* __restrict__ attn,
                                              short* __restrict__ attnB) {
    __shared__ float wred[4];
    __shared__ float wred2[4];
    const int row = blockIdx.x;
    const int tid = threadIdx.x;
    const float ss = s_src[row];
    const int4v* adj4 = (const int4v*)(adj + (long)row * NN);
    const f32x4* sd4 = (const f32x4*)s_dst;
    float v[16];
    float vmax = -3e38f;
#pragma unroll
    for (int c = 0; c < 4; c++) {
        int idx = c * 256 + tid;
        int4v a = __builtin_nontemporal_load(&adj4[idx]);
        f32x4 d = sd4[idx];
        float x0 = ss + d.x; x0 = x0 > 0.f ? x0 : SLOPEC * x0; x0 = a.x > 0 ? x0 : NEG_INFC;
        float x1 = ss + d.y; x1 = x1 > 0.f ? x1 : SLOPEC * x1; x1 = a.y > 0 ? x1 : NEG_INFC;
        float x2 = ss + d.z; x2 = x2 > 0.f ? x2 : SLOPEC * x2; x2 = a.z > 0 ? x2 : NEG_INFC;
        float x3 = ss + d.w; x3 = x3 > 0.f ? x3 : SLOPEC * x3; x3 = a.w > 0 ? x3 : NEG_INFC;
        v[c * 4 + 0] = x0; v[c * 4 + 1] = x1; v[c * 4 + 2] = x2; v[c * 4 + 3] = x3;
        vmax = fmaxf(vmax, fmaxf(fmaxf(x0, x1), fmaxf(x2, x3)));
    }
#pragma unroll
    for (int off = 32; off; off >>= 1) vmax = fmaxf(vmax, __shfl_xor(vmax, off));
    if ((tid & 63) == 0) wred[tid >> 6] = vmax;
    __syncthreads();
    vmax = fmaxf(fmaxf(wred[0], wred[1]), fmaxf(wred[2], wred[3]));

    float sum = 0.f;
#pragma unroll
    for (int c = 0; c < 16; c++) {
        v[c] = __expf(v[c] - vmax);
        sum += v[c];
    }
#pragma unroll
    for (int off = 32; off; off >>= 1) sum += __shfl_xor(sum, off);
    if ((tid & 63) == 0) wred2[tid >> 6] = sum;
    __syncthreads();
    sum = wred2[0] + wred2[1] + wred2[2] + wred2[3];
    const float inv = 1.0f / sum;

    f32x4* o4 = (f32x4*)(attn + (long)row * NN);
    short4v* b4 = (short4v*)(attnB + (long)row * NN);
#pragma unroll
    for (int c = 0; c < 4; c++) {
        int idx = c * 256 + tid;
        f32x4 o;
        o.x = v[c * 4 + 0] * inv; o.y = v[c * 4 + 1] * inv;
        o.z = v[c * 4 + 2] * inv; o.w = v[c * 4 + 3] * inv;
        __builtin_nontemporal_store(o, &o4[idx]);
        short4v sb;
        sb.x = f2bf(o.x); sb.y = f2bf(o.y); sb.z = f2bf(o.z); sb.w = f2bf(o.w);
        b4[idx] = sb;
    }
}

// ---------------------------------------------------------------------------
// pool mean + classifier + 2-way softmax
// ---------------------------------------------------------------------------
__global__ __launch_bounds__(256) void k_final(const float* __restrict__ pool_acc,
                                               const float* __restrict__ clf_w,
                                               const float* __restrict__ clf_b,
                                               float* __restrict__ out_pool,
                                               float* __restrict__ out_label) {
    __shared__ float r0[4], r1[4];
    const int tid = threadIdx.x;
    float l0 = 0.f, l1 = 0.f;
#pragma unroll
    for (int q = 0; q < 4; q++) {
        int f = q * 256 + tid;
        float p = pool_acc[f] * (1.0f / NN);
        out_pool[f] = p;
        l0 += p * clf_w[f * 2 + 0];
        l1 += p * clf_w[f * 2 + 1];
    }
#pragma unroll
    for (int off = 32; off; off >>= 1) {
        l0 += __shfl_xor(l0, off);
        l1 += __shfl_xor(l1, off);
    }
    if ((tid & 63) == 0) { r0[tid >> 6] = l0; r1[tid >> 6] = l1; }
    __syncthreads();
    if (tid == 0) {
        float L0 = r0[0] + r0[1] + r0[2] + r0[3] + clf_b[0];
        float L1 = r1[0] + r1[1] + r1[2] + r1[3] + clf_b[1];
        float m = fmaxf(L0, L1);
        float e0 = __expf(L0 - m), e1 = __expf(L1 - m);
        float s = e0 + e1;
        out_label[0] = e0 / s;
        out_label[1] = e1 / s;
    }
}

// ---------------------------------------------------------------------------
extern "C" void kernel_launch(void* const* d_in, const int* in_sizes, int n_in,
                              void* d_out, int out_size, void* d_ws,
                              size_t ws_size, hipStream_t stream) {
    const int* inSen = (const int*)d_in[0];
    const int* adj = (const int*)d_in[1];
    const float* emb = (const float*)d_in[2];
    const float* W = (const float*)d_in[3];
    const float* a_src = (const float*)d_in[4];
    const float* a_dst = (const float*)d_in[5];
    const float* clf_w = (const float*)d_in[6];
    const float* clf_b = (const float*)d_in[7];

    float* out = (float*)d_out;
    float* out_pool = out;
    float* attn = out + 1024;
    float* sentence = out + 1024 + (long)NN * NN;
    float* out_label = out + 1024 + (long)NN * NN + (long)NN * WF;

    // ws layout:
    //   X     [NN][ED]    bf16   8 MB  @ 0
    //   Wt    [WF][ED]    bf16   2 MB  @ 8 MB
    //   Ht    [WF][NN]    bf16   8 MB  @ 10 MB
    //   attnB [NN][NN]    bf16  33.6MB @ 18 MB
    //   s_src/s_dst/pool         small @ 52 MB
    char* ws = (char*)d_ws;
    short* X = (short*)ws;
    short* Wt = (short*)(ws + (8l << 20));
    short* Ht = (short*)(ws + (10l << 20));
    short* attnB = (short*)(ws + (18l << 20));
    float* s_src = (float*)(ws + (52l << 20));
    float* s_dst = s_src + NN;
    float* pool = s_dst + NN;

    (void)hipMemsetAsync(s_src, 0, (2 * NN + WF) * sizeof(float), stream);
    // sentence is accumulated via split-K atomics in GEMM2 -> pre-zero it
    (void)hipMemsetAsync(sentence, 0, (long)NN * WF * sizeof(float), stream);

    k_prep<<<256 + NN, 256, 0, stream>>>(W, Wt, inSen, emb, X);

    // GEMM1: Ht[f][i] = sum_k Wt[f][k] * X[i][k]
    // M=WF, N=NN, K=ED; BM=64, BN=128 -> 512 blocks, bf16 out + fused scores
    gemm_bt2<64, 128, 0><<<dim3(NN / 128, WF / 64, 1), 256, 0, stream>>>(
        Wt, X, NN, ED, ED, Ht, a_src, a_dst, s_src, s_dst, nullptr);

    k_attn<<<NN, 256, 0, stream>>>(adj, s_src, s_dst, attn, attnB);

    // GEMM2: sentence[i][f] = sum_k attnB[i][k] * Ht[f][k]
    // M=NN, N=WF, K=NN; split-K=2 -> 512 blocks (2/CU), fp32 atomic
    // accumulation into sentence + fused pool colsum (reduce2 eliminated)
    gemm_bt2<128, 128, 1><<<dim3(WF / 128, NN / 128, 2), 256, 0, stream>>>(
        attnB, Ht, WF, NN, NN / 2, sentence,
        nullptr, nullptr, nullptr, nullptr, pool);

    k_final<<<1, 256, 0, stream>>>(pool, clf_w, clf_b, out_pool, out_label);
}

// Round 2
// 406.784 us; speedup vs baseline: 1.0674x; 1.0349x over previous
//
#include <hip/hip_runtime.h>
#include <hip/hip_bf16.h>

#define NN 4096      // nodes
#define ED 1024      // edim
#define WF 1024      // wfeat
#define SLOPEC 0.01f
#define NEG_INFC -1e9f

typedef __attribute__((ext_vector_type(8))) short bf16x8;
typedef __attribute__((ext_vector_type(4))) short short4v;
typedef __attribute__((ext_vector_type(4))) float f32x4;
typedef __attribute__((ext_vector_type(4))) int int4v;

__device__ __forceinline__ float bf2f(short s) {
    union { unsigned u; float f; } v;
    v.u = ((unsigned)(unsigned short)s) << 16;
    return v.f;
}
__device__ __forceinline__ short f2bf(float f) {
    unsigned u = __float_as_uint(f);
    unsigned r = u + 0x7FFFu + ((u >> 16) & 1u);   // RNE (finite data)
    return (short)(r >> 16);
}

typedef __attribute__((address_space(3))) unsigned lds_u32;
typedef const __attribute__((address_space(1))) unsigned gbl_u32;
__device__ __forceinline__ void g2l16(const short* g, short* l) {
    __builtin_amdgcn_global_load_lds((gbl_u32*)g, (lds_u32*)l, 16, 0, 0);
}

// ---------------------------------------------------------------------------
// Fused prep:
//  blocks [0,256): transpose+convert W [ED][WF] fp32 -> Wt [WF][ED] bf16
//    blocks [0,9) additionally zero s_src/s_dst/pool (9216 floats)
//  blocks [256,256+NN): gather+convert X[i][k] = bf16(emb[inSen[i]][k])
// ---------------------------------------------------------------------------
__global__ __launch_bounds__(256) void k_prep(const float* __restrict__ W,
                                              short* __restrict__ Wt,
                                              const int* __restrict__ inSen,
                                              const float* __restrict__ emb,
                                              short* __restrict__ X,
                                              float* __restrict__ zbase) {
    if (blockIdx.x < 256) {
        if (blockIdx.x < 9) {
            // zero s_src (NN) + s_dst (NN) + pool (WF) = 9216 floats
            f32x4 z = {0.f, 0.f, 0.f, 0.f};
            *(f32x4*)(zbase + blockIdx.x * 1024 + threadIdx.x * 4) = z;
        }
        __shared__ float t[64][65];
        const int n0 = (blockIdx.x & 15) * 64, k0 = (blockIdx.x >> 4) * 64;
        const int tx = threadIdx.x & 63, ty = threadIdx.x >> 6;
#pragma unroll
        for (int p = 0; p < 16; p++) {
            int r = p * 4 + ty;
            t[r][tx] = W[(long)(k0 + r) * WF + n0 + tx];
        }
        __syncthreads();
#pragma unroll
        for (int p = 0; p < 16; p++) {
            int r = p * 4 + ty;  // n index
            Wt[(long)(n0 + r) * ED + k0 + tx] = f2bf(t[tx][r]);
        }
    } else {
        const int row = blockIdx.x - 256;
        const int tid = threadIdx.x;
        const long idx = inSen[row];
        const float4 v = ((const float4*)(emb + idx * ED))[tid];
        short4v s;
        s.x = f2bf(v.x); s.y = f2bf(v.y); s.z = f2bf(v.z); s.w = f2bf(v.w);
        *(short4v*)(X + (long)row * ED + tid * 4) = s;
    }
}

// ---------------------------------------------------------------------------
// GEMM (m97 structure): C[M][N] = A[M][K] * Bt[N][K], bf16 in.
// Tile BM x BN, BK=32, 256 thr = 4 waves (2x2). global_load_lds width=16.
// MODE 0: bf16 C store via LDS repack + fused s_src/s_dst column scores.
// MODE 1: direct fp32 C store + fused pool colsum (atomic on pool only).
// SWAPXY: blockIdx.x indexes M-tiles (m-fast dispatch -> B-panel L2 reuse).
// ---------------------------------------------------------------------------
template <int BM, int BN, int MODE, bool SWAPXY>
__global__ __launch_bounds__(256, 2) void gemm_bt2(
    const short* __restrict__ A, const short* __restrict__ Bt,
    int N, int K, int Kc, void* __restrict__ Cout,
    const float* __restrict__ a_src, const float* __restrict__ a_dst,
    float* __restrict__ s_src, float* __restrict__ s_dst,
    float* __restrict__ pool) {
    constexpr int TM = BM / 32;           // m-frags per wave
    constexpr int TN = BN / 32;           // n-frags per wave
    constexpr int STAGE = BM * 32 + BN * 32;
    constexpr int SMEMSZ = (MODE == 0 && BM * BN > STAGE) ? BM * BN : STAGE;
    __shared__ __align__(16) short smem[SMEMSZ];
    short* sA = smem;
    short* sB = smem + BM * 32;

    const int tid = threadIdx.x;
    const int lane = tid & 63;
    const int wid = tid >> 6;
    const int wm = wid >> 1, wn = wid & 1;
    const int n0 = (SWAPXY ? blockIdx.y : blockIdx.x) * BN;
    const int m0 = (SWAPXY ? blockIdx.x : blockIdx.y) * BM;
    const int ks = blockIdx.z * Kc;

    const int srow = tid >> 2;        // 0..63
    const int sc8 = (tid & 3) * 8;    // 0,8,16,24
    const int l15 = lane & 15;
    const int lhi = lane >> 4;

    f32x4 acc[TM][TN];
#pragma unroll
    for (int t = 0; t < TM; t++)
#pragma unroll
        for (int u = 0; u < TN; u++) acc[t][u] = (f32x4){0.f, 0.f, 0.f, 0.f};

    const short* Ab = A + (long)(m0 + srow) * K + ks + sc8;
    const short* Bb = Bt + (long)(n0 + srow) * K + ks + sc8;
    const long rstep = (long)64 * K;   // 64 rows

    for (int k0 = 0; k0 < Kc; k0 += 32) {
#pragma unroll
        for (int p = 0; p < BM / 64; p++)
            g2l16(Ab + p * rstep + k0, sA + (p * 256 + wid * 64) * 8);
#pragma unroll
        for (int p = 0; p < BN / 64; p++)
            g2l16(Bb + p * rstep + k0, sB + (p * 256 + wid * 64) * 8);
        __syncthreads();   // drains vmcnt for global_load_lds

        bf16x8 af[TM], bfr[TN];
#pragma unroll
        for (int t = 0; t < TM; t++)
            af[t] = *(const bf16x8*)&sA[(wm * (BM / 2) + t * 16 + l15) * 32 + lhi * 8];
#pragma unroll
        for (int u = 0; u < TN; u++)
            bfr[u] = *(const bf16x8*)&sB[(wn * (BN / 2) + u * 16 + l15) * 32 + lhi * 8];
#pragma unroll
        for (int t = 0; t < TM; t++)
#pragma unroll
            for (int u = 0; u < TN; u++)
                acc[t][u] = __builtin_amdgcn_mfma_f32_16x16x32_bf16(
                    af[t], bfr[u], acc[t][u], 0, 0, 0);
        __syncthreads();
    }

    // Epilogue. D mapping per 16x16 tile: col = l15, row = lhi*4 + r
    if (MODE == 0) {
        short* sT = smem;   // safe: last loop iteration ended with a barrier
#pragma unroll
        for (int t = 0; t < TM; t++)
#pragma unroll
            for (int u = 0; u < TN; u++)
#pragma unroll
                for (int r = 0; r < 4; r++) {
                    int m = wm * (BM / 2) + t * 16 + lhi * 4 + r;
                    int n = wn * (BN / 2) + u * 16 + l15;
                    sT[m * BN + n] = f2bf(acc[t][u][r]);
                }
        __syncthreads();
        short* C = (short*)Cout;
#pragma unroll
        for (int q = 0; q < BM * BN / 2048; q++) {
            int idx = q * 256 + tid;
            int row = idx / (BN / 8);
            int c8 = (idx % (BN / 8)) * 8;
            *(bf16x8*)(C + (long)(m0 + row) * N + n0 + c8) =
                *(const bf16x8*)&sT[row * BN + c8];
        }
        // s_src[n] += sum_m Ht[m][n]*a_src[m] over this block's m-range
        float ps[TN], pd[TN];
#pragma unroll
        for (int u = 0; u < TN; u++) { ps[u] = 0.f; pd[u] = 0.f; }
#pragma unroll
        for (int t = 0; t < TM; t++)
#pragma unroll
            for (int r = 0; r < 4; r++) {
                int m = m0 + wm * (BM / 2) + t * 16 + lhi * 4 + r;
                float as = a_src[m], ad = a_dst[m];
#pragma unroll
                for (int u = 0; u < TN; u++) {
                    ps[u] += acc[t][u][r] * as;
                    pd[u] += acc[t][u][r] * ad;
                }
            }
#pragma unroll
        for (int u = 0; u < TN; u++) {
            ps[u] += __shfl_xor(ps[u], 16); ps[u] += __shfl_xor(ps[u], 32);
            pd[u] += __shfl_xor(pd[u], 16); pd[u] += __shfl_xor(pd[u], 32);
        }
        if (lane < 16) {
#pragma unroll
            for (int u = 0; u < TN; u++) {
                int n = n0 + wn * (BN / 2) + u * 16 + lane;
                atomicAdd(s_src + n, ps[u]);
                atomicAdd(s_dst + n, pd[u]);
            }
        }
    } else {
        // MODE 1: direct fp32 store (no split-K, no RMW) + pool colsum.
        float* C = (float*)Cout;
        float pp[TN];
#pragma unroll
        for (int u = 0; u < TN; u++) pp[u] = 0.f;
#pragma unroll
        for (int t = 0; t < TM; t++)
#pragma unroll
            for (int u = 0; u < TN; u++)
#pragma unroll
                for (int r = 0; r < 4; r++) {
                    int m = wm * (BM / 2) + t * 16 + lhi * 4 + r;
                    int n = wn * (BN / 2) + u * 16 + l15;
                    C[(long)(m0 + m) * N + n0 + n] = acc[t][u][r];
                    pp[u] += acc[t][u][r];
                }
#pragma unroll
        for (int u = 0; u < TN; u++) {
            pp[u] += __shfl_xor(pp[u], 16);
            pp[u] += __shfl_xor(pp[u], 32);
        }
        if (lane < 16) {
#pragma unroll
            for (int u = 0; u < TN; u++) {
                int n = n0 + wn * (BN / 2) + u * 16 + lane;
                atomicAdd(pool + n, pp[u]);
            }
        }
    }
}

// ---------------------------------------------------------------------------
// Masked softmax row -> attn fp32 (d_out, NT) + attnB bf16 (ws, GEMM2 A)
// ---------------------------------------------------------------------------
__global__ __launch_bounds__(256) void k_attn(const int* __restrict__ adj,
                                              const float* __restrict__ s_src,
                                              const float* __restrict__ s_dst,
                                              float* __restrict__ attn,
                                              short* __restrict__ attnB) {
    __shared__ float wred[4];
    __shared__ float wred2[4];
    const int row = blockIdx.x;
    const int tid = threadIdx.x;
    const float ss = s_src[row];
    const int4v* adj4 = (const int4v*)(adj + (long)row * NN);
    const f32x4* sd4 = (const f32x4*)s_dst;
    float v[16];
    float vmax = -3e38f;
#pragma unroll
    for (int c = 0; c < 4; c++) {
        int idx = c * 256 + tid;
        int4v a = __builtin_nontemporal_load(&adj4[idx]);
        f32x4 d = sd4[idx];
        float x0 = ss + d.x; x0 = x0 > 0.f ? x0 : SLOPEC * x0; x0 = a.x > 0 ? x0 : NEG_INFC;
        float x1 = ss + d.y; x1 = x1 > 0.f ? x1 : SLOPEC * x1; x1 = a.y > 0 ? x1 : NEG_INFC;
        float x2 = ss + d.z; x2 = x2 > 0.f ? x2 : SLOPEC * x2; x2 = a.z > 0 ? x2 : NEG_INFC;
        float x3 = ss + d.w; x3 = x3 > 0.f ? x3 : SLOPEC * x3; x3 = a.w > 0 ? x3 : NEG_INFC;
        v[c * 4 + 0] = x0; v[c * 4 + 1] = x1; v[c * 4 + 2] = x2; v[c * 4 + 3] = x3;
        vmax = fmaxf(vmax, fmaxf(fmaxf(x0, x1), fmaxf(x2, x3)));
    }
#pragma unroll
    for (int off = 32; off; off >>= 1) vmax = fmaxf(vmax, __shfl_xor(vmax, off));
    if ((tid & 63) == 0) wred[tid >> 6] = vmax;
    __syncthreads();
    vmax = fmaxf(fmaxf(wred[0], wred[1]), fmaxf(wred[2], wred[3]));

    float sum = 0.f;
#pragma unroll
    for (int c = 0; c < 16; c++) {
        v[c] = __expf(v[c] - vmax);
        sum += v[c];
    }
#pragma unroll
    for (int off = 32; off; off >>= 1) sum += __shfl_xor(sum, off);
    if ((tid & 63) == 0) wred2[tid >> 6] = sum;
    __syncthreads();
    sum = wred2[0] + wred2[1] + wred2[2] + wred2[3];
    const float inv = 1.0f / sum;

    f32x4* o4 = (f32x4*)(attn + (long)row * NN);
    short4v* b4 = (short4v*)(attnB + (long)row * NN);
#pragma unroll
    for (int c = 0; c < 4; c++) {
        int idx = c * 256 + tid;
        f32x4 o;
        o.x = v[c * 4 + 0] * inv; o.y = v[c * 4 + 1] * inv;
        o.z = v[c * 4 + 2] * inv; o.w = v[c * 4 + 3] * inv;
        __builtin_nontemporal_store(o, &o4[idx]);
        short4v sb;
        sb.x = f2bf(o.x); sb.y = f2bf(o.y); sb.z = f2bf(o.z); sb.w = f2bf(o.w);
        b4[idx] = sb;
    }
}

// ---------------------------------------------------------------------------
// pool mean + classifier + 2-way softmax
// ---------------------------------------------------------------------------
__global__ __launch_bounds__(256) void k_final(const float* __restrict__ pool_acc,
                                               const float* __restrict__ clf_w,
                                               const float* __restrict__ clf_b,
                                               float* __restrict__ out_pool,
                                               float* __restrict__ out_label) {
    __shared__ float r0[4], r1[4];
    const int tid = threadIdx.x;
    float l0 = 0.f, l1 = 0.f;
#pragma unroll
    for (int q = 0; q < 4; q++) {
        int f = q * 256 + tid;
        float p = pool_acc[f] * (1.0f / NN);
        out_pool[f] = p;
        l0 += p * clf_w[f * 2 + 0];
        l1 += p * clf_w[f * 2 + 1];
    }
#pragma unroll
    for (int off = 32; off; off >>= 1) {
        l0 += __shfl_xor(l0, off);
        l1 += __shfl_xor(l1, off);
    }
    if ((tid & 63) == 0) { r0[tid >> 6] = l0; r1[tid >> 6] = l1; }
    __syncthreads();
    if (tid == 0) {
        float L0 = r0[0] + r0[1] + r0[2] + r0[3] + clf_b[0];
        float L1 = r1[0] + r1[1] + r1[2] + r1[3] + clf_b[1];
        float m = fmaxf(L0, L1);
        float e0 = __expf(L0 - m), e1 = __expf(L1 - m);
        float s = e0 + e1;
        out_label[0] = e0 / s;
        out_label[1] = e1 / s;
    }
}

// ---------------------------------------------------------------------------
extern "C" void kernel_launch(void* const* d_in, const int* in_sizes, int n_in,
                              void* d_out, int out_size, void* d_ws,
                              size_t ws_size, hipStream_t stream) {
    const int* inSen = (const int*)d_in[0];
    const int* adj = (const int*)d_in[1];
    const float* emb = (const float*)d_in[2];
    const float* W = (const float*)d_in[3];
    const float* a_src = (const float*)d_in[4];
    const float* a_dst = (const float*)d_in[5];
    const float* clf_w = (const float*)d_in[6];
    const float* clf_b = (const float*)d_in[7];

    float* out = (float*)d_out;
    float* out_pool = out;
    float* attn = out + 1024;
    float* sentence = out + 1024 + (long)NN * NN;
    float* out_label = out + 1024 + (long)NN * NN + (long)NN * WF;

    // ws layout:
    //   X     [NN][ED]    bf16   8 MB  @ 0
    //   Wt    [WF][ED]    bf16   2 MB  @ 8 MB
    //   Ht    [WF][NN]    bf16   8 MB  @ 10 MB
    //   attnB [NN][NN]    bf16  33.6MB @ 18 MB
    //   s_src/s_dst/pool (9216 f, zeroed in k_prep) @ 52 MB
    char* ws = (char*)d_ws;
    short* X = (short*)ws;
    short* Wt = (short*)(ws + (8l << 20));
    short* Ht = (short*)(ws + (10l << 20));
    short* attnB = (short*)(ws + (18l << 20));
    float* s_src = (float*)(ws + (52l << 20));
    float* s_dst = s_src + NN;
    float* pool = s_dst + NN;

    k_prep<<<256 + NN, 256, 0, stream>>>(W, Wt, inSen, emb, X, s_src);

    // GEMM1: Ht[f][i] = sum_k Wt[f][k] * X[i][k]
    // M=WF, N=NN, K=ED; BM=64, BN=128 -> 512 blocks, bf16 out + fused scores
    gemm_bt2<64, 128, 0, false><<<dim3(NN / 128, WF / 64, 1), 256, 0, stream>>>(
        Wt, X, NN, ED, ED, Ht, a_src, a_dst, s_src, s_dst, nullptr);

    k_attn<<<NN, 256, 0, stream>>>(adj, s_src, s_dst, attn, attnB);

    // GEMM2: sentence[i][f] = sum_k attnB[i][k] * Ht[f][k]
    // M=NN, N=WF, K=NN. BM=64, BN=128, no split-K -> 64x8 = 512 blocks
    // (2/CU), m-fast dispatch so 64-block groups share one Ht B-panel.
    // Direct fp32 stores (no memset, no RMW) + fused pool colsum.
    gemm_bt2<64, 128, 1, true><<<dim3(NN / 64, WF / 128, 1), 256, 0, stream>>>(
        attnB, Ht, WF, NN, NN, sentence,
        nullptr, nullptr, nullptr, nullptr, pool);

    k_final<<<1, 256, 0, stream>>>(pool, clf_w, clf_b, out_pool, out_label);
}

// Round 4
// 393.262 us; speedup vs baseline: 1.1041x; 1.0344x over previous
//
#include <hip/hip_runtime.h>
#include <hip/hip_bf16.h>

#define NN 4096      // nodes
#define ED 1024      // edim
#define WF 1024      // wfeat
#define SLOPEC 0.01f
#define NEG_INFC -1e9f

typedef __attribute__((ext_vector_type(8))) short bf16x8;
typedef __attribute__((ext_vector_type(4))) short short4v;
typedef __attribute__((ext_vector_type(4))) float f32x4;
typedef __attribute__((ext_vector_type(4))) int int4v;

__device__ __forceinline__ float bf2f(short s) {
    union { unsigned u; float f; } v;
    v.u = ((unsigned)(unsigned short)s) << 16;
    return v.f;
}
__device__ __forceinline__ short f2bf(float f) {
    unsigned u = __float_as_uint(f);
    unsigned r = u + 0x7FFFu + ((u >> 16) & 1u);   // RNE (finite data)
    return (short)(r >> 16);
}

typedef __attribute__((address_space(3))) unsigned lds_u32;
typedef const __attribute__((address_space(1))) unsigned gbl_u32;
__device__ __forceinline__ void g2l16(const short* g, short* l) {
    __builtin_amdgcn_global_load_lds((gbl_u32*)g, (lds_u32*)l, 16, 0, 0);
}

// ---------------------------------------------------------------------------
// Fused prep:
//  blocks [0,256): transpose+convert W [ED][WF] fp32 -> Wt [WF][ED] bf16
//    blocks [0,9) additionally zero s_src/s_dst/pool (9216 floats)
//  blocks [256,256+NN): gather+convert X[i][k] = bf16(emb[inSen[i]][k])
// ---------------------------------------------------------------------------
__global__ __launch_bounds__(256) void k_prep(const float* __restrict__ W,
                                              short* __restrict__ Wt,
                                              const int* __restrict__ inSen,
                                              const float* __restrict__ emb,
                                              short* __restrict__ X,
                                              float* __restrict__ zbase) {
    if (blockIdx.x < 256) {
        if (blockIdx.x < 9) {
            // zero s_src (NN) + s_dst (NN) + pool (WF) = 9216 floats
            f32x4 z = {0.f, 0.f, 0.f, 0.f};
            *(f32x4*)(zbase + blockIdx.x * 1024 + threadIdx.x * 4) = z;
        }
        __shared__ float t[64][65];
        const int n0 = (blockIdx.x & 15) * 64, k0 = (blockIdx.x >> 4) * 64;
        const int tx = threadIdx.x & 63, ty = threadIdx.x >> 6;
#pragma unroll
        for (int p = 0; p < 16; p++) {
            int r = p * 4 + ty;
            t[r][tx] = W[(long)(k0 + r) * WF + n0 + tx];
        }
        __syncthreads();
#pragma unroll
        for (int p = 0; p < 16; p++) {
            int r = p * 4 + ty;  // n index
            Wt[(long)(n0 + r) * ED + k0 + tx] = f2bf(t[tx][r]);
        }
    } else {
        const int row = blockIdx.x - 256;
        const int tid = threadIdx.x;
        const long idx = inSen[row];
        const float4 v = ((const float4*)(emb + idx * ED))[tid];
        short4v s;
        s.x = f2bf(v.x); s.y = f2bf(v.y); s.z = f2bf(v.z); s.w = f2bf(v.w);
        *(short4v*)(X + (long)row * ED + tid * 4) = s;
    }
}

// ---------------------------------------------------------------------------
// GEMM (m97 structure, BK=64): C[M][N] = A[M][K] * Bt[N][K], bf16 in.
// Tile BM x BN, 256 thr = 4 waves (2x2). global_load_lds width=16.
// BK=64 staged as two [rows][32] sub-chunks -> one barrier pair per 64-K
// (halves the vmcnt-drain count vs BK=32). MFMA k-order preserved.
// MODE 0: bf16 C store via LDS repack + fused s_src/s_dst column scores.
// MODE 1: direct fp32 C store + fused pool colsum (atomic on pool only).
// SWAPXY: blockIdx.x indexes M-tiles (m-fast dispatch -> B-panel L2 reuse).
// ---------------------------------------------------------------------------
template <int BM, int BN, int MODE, bool SWAPXY>
__global__ __launch_bounds__(256, 2) void gemm_bt2(
    const short* __restrict__ A, const short* __restrict__ Bt,
    int N, int K, int Kc, void* __restrict__ Cout,
    const float* __restrict__ a_src, const float* __restrict__ a_dst,
    float* __restrict__ s_src, float* __restrict__ s_dst,
    float* __restrict__ pool) {
    constexpr int TM = BM / 32;           // m-frags per wave
    constexpr int TN = BN / 32;           // n-frags per wave
    constexpr int STAGE = (BM + BN) * 64;               // BK=64
    constexpr int SMEMSZ = (MODE == 0 && BM * BN > STAGE) ? BM * BN : STAGE;
    __shared__ __align__(16) short smem[SMEMSZ];
    short* sA = smem;                 // [2][BM][32]
    short* sB = smem + BM * 64;       // [2][BN][32]

    const int tid = threadIdx.x;
    const int lane = tid & 63;
    const int wid = tid >> 6;
    const int wm = wid >> 1, wn = wid & 1;
    const int n0 = (SWAPXY ? blockIdx.y : blockIdx.x) * BN;
    const int m0 = (SWAPXY ? blockIdx.x : blockIdx.y) * BM;
    const int ks = blockIdx.z * Kc;

    const int srow = tid >> 2;        // 0..63
    const int sc8 = (tid & 3) * 8;    // 0,8,16,24
    const int l15 = lane & 15;
    const int lhi = lane >> 4;

    f32x4 acc[TM][TN];
#pragma unroll
    for (int t = 0; t < TM; t++)
#pragma unroll
        for (int u = 0; u < TN; u++) acc[t][u] = (f32x4){0.f, 0.f, 0.f, 0.f};

    const short* Ab = A + (long)(m0 + srow) * K + ks + sc8;
    const short* Bb = Bt + (long)(n0 + srow) * K + ks + sc8;
    const long rstep = (long)64 * K;   // 64 rows

    for (int k0 = 0; k0 < Kc; k0 += 64) {
#pragma unroll
        for (int c = 0; c < 2; c++) {
#pragma unroll
            for (int p = 0; p < BM / 64; p++)
                g2l16(Ab + p * rstep + k0 + c * 32,
                      sA + c * (BM * 32) + (p * 256 + wid * 64) * 8);
#pragma unroll
            for (int p = 0; p < BN / 64; p++)
                g2l16(Bb + p * rstep + k0 + c * 32,
                      sB + c * (BN * 32) + (p * 256 + wid * 64) * 8);
        }
        __syncthreads();   // drains vmcnt for global_load_lds (once per 64-K)

#pragma unroll
        for (int c = 0; c < 2; c++) {
            bf16x8 af[TM], bfr[TN];
#pragma unroll
            for (int t = 0; t < TM; t++)
                af[t] = *(const bf16x8*)&sA[c * (BM * 32) +
                        (wm * (BM / 2) + t * 16 + l15) * 32 + lhi * 8];
#pragma unroll
            for (int u = 0; u < TN; u++)
                bfr[u] = *(const bf16x8*)&sB[c * (BN * 32) +
                         (wn * (BN / 2) + u * 16 + l15) * 32 + lhi * 8];
#pragma unroll
            for (int t = 0; t < TM; t++)
#pragma unroll
                for (int u = 0; u < TN; u++)
                    acc[t][u] = __builtin_amdgcn_mfma_f32_16x16x32_bf16(
                        af[t], bfr[u], acc[t][u], 0, 0, 0);
        }
        __syncthreads();
    }

    // Epilogue. D mapping per 16x16 tile: col = l15, row = lhi*4 + r
    if (MODE == 0) {
        short* sT = smem;   // safe: last loop iteration ended with a barrier
#pragma unroll
        for (int t = 0; t < TM; t++)
#pragma unroll
            for (int u = 0; u < TN; u++)
#pragma unroll
                for (int r = 0; r < 4; r++) {
                    int m = wm * (BM / 2) + t * 16 + lhi * 4 + r;
                    int n = wn * (BN / 2) + u * 16 + l15;
                    sT[m * BN + n] = f2bf(acc[t][u][r]);
                }
        __syncthreads();
        short* C = (short*)Cout;
#pragma unroll
        for (int q = 0; q < BM * BN / 2048; q++) {
            int idx = q * 256 + tid;
            int row = idx / (BN / 8);
            int c8 = (idx % (BN / 8)) * 8;
            *(bf16x8*)(C + (long)(m0 + row) * N + n0 + c8) =
                *(const bf16x8*)&sT[row * BN + c8];
        }
        // s_src[n] += sum_m Ht[m][n]*a_src[m] over this block's m-range
        float ps[TN], pd[TN];
#pragma unroll
        for (int u = 0; u < TN; u++) { ps[u] = 0.f; pd[u] = 0.f; }
#pragma unroll
        for (int t = 0; t < TM; t++)
#pragma unroll
            for (int r = 0; r < 4; r++) {
                int m = m0 + wm * (BM / 2) + t * 16 + lhi * 4 + r;
                float as = a_src[m], ad = a_dst[m];
#pragma unroll
                for (int u = 0; u < TN; u++) {
                    ps[u] += acc[t][u][r] * as;
                    pd[u] += acc[t][u][r] * ad;
                }
            }
#pragma unroll
        for (int u = 0; u < TN; u++) {
            ps[u] += __shfl_xor(ps[u], 16); ps[u] += __shfl_xor(ps[u], 32);
            pd[u] += __shfl_xor(pd[u], 16); pd[u] += __shfl_xor(pd[u], 32);
        }
        if (lane < 16) {
#pragma unroll
            for (int u = 0; u < TN; u++) {
                int n = n0 + wn * (BN / 2) + u * 16 + lane;
                atomicAdd(s_src + n, ps[u]);
                atomicAdd(s_dst + n, pd[u]);
            }
        }
    } else {
        // MODE 1: direct fp32 store (no split-K, no RMW) + pool colsum.
        float* C = (float*)Cout;
        float pp[TN];
#pragma unroll
        for (int u = 0; u < TN; u++) pp[u] = 0.f;
#pragma unroll
        for (int t = 0; t < TM; t++)
#pragma unroll
            for (int u = 0; u < TN; u++)
#pragma unroll
                for (int r = 0; r < 4; r++) {
                    int m = wm * (BM / 2) + t * 16 + lhi * 4 + r;
                    int n = wn * (BN / 2) + u * 16 + l15;
                    C[(long)(m0 + m) * N + n0 + n] = acc[t][u][r];
                    pp[u] += acc[t][u][r];
                }
#pragma unroll
        for (int u = 0; u < TN; u++) {
            pp[u] += __shfl_xor(pp[u], 16);
            pp[u] += __shfl_xor(pp[u], 32);
        }
        if (lane < 16) {
#pragma unroll
            for (int u = 0; u < TN; u++) {
                int n = n0 + wn * (BN / 2) + u * 16 + lane;
                atomicAdd(pool + n, pp[u]);
            }
        }
    }
}

// ---------------------------------------------------------------------------
// Masked softmax row -> attn fp32 (d_out, NT) + attnB bf16 (ws, GEMM2 A)
// ---------------------------------------------------------------------------
__global__ __launch_bounds__(256) void k_attn(const int* __restrict__ adj,
                                              const float* __restrict__ s_src,
                                              const float* __restrict__ s_dst,
                                              float* __restrict__ attn,
                                              short* __restrict__ attnB) {
    __shared__ float wred[4];
    __shared__ float wred2[4];
    const int row = blockIdx.x;
    const int tid = threadIdx.x;
    const float ss = s_src[row];
    const int4v* adj4 = (const int4v*)(adj + (long)row * NN);
    const f32x4* sd4 = (const f32x4*)s_dst;
    float v[16];
    float vmax = -3e38f;
#pragma unroll
    for (int c = 0; c < 4; c++) {
        int idx = c * 256 + tid;
        int4v a = __builtin_nontemporal_load(&adj4[idx]);
        f32x4 d = sd4[idx];
        float x0 = ss + d.x; x0 = x0 > 0.f ? x0 : SLOPEC * x0; x0 = a.x > 0 ? x0 : NEG_INFC;
        float x1 = ss + d.y; x1 = x1 > 0.f ? x1 : SLOPEC * x1; x1 = a.y > 0 ? x1 : NEG_INFC;
        float x2 = ss + d.z; x2 = x2 > 0.f ? x2 : SLOPEC * x2; x2 = a.z > 0 ? x2 : NEG_INFC;
        float x3 = ss + d.w; x3 = x3 > 0.f ? x3 : SLOPEC * x3; x3 = a.w > 0 ? x3 : NEG_INFC;
        v[c * 4 + 0] = x0; v[c * 4 + 1] = x1; v[c * 4 + 2] = x2; v[c * 4 + 3] = x3;
        vmax = fmaxf(vmax, fmaxf(fmaxf(x0, x1), fmaxf(x2, x3)));
    }
#pragma unroll
    for (int off = 32; off; off >>= 1) vmax = fmaxf(vmax, __shfl_xor(vmax, off));
    if ((tid & 63) == 0) wred[tid >> 6] = vmax;
    __syncthreads();
    vmax = fmaxf(fmaxf(wred[0], wred[1]), fmaxf(wred[2], wred[3]));

    float sum = 0.f;
#pragma unroll
    for (int c = 0; c < 16; c++) {
        v[c] = __expf(v[c] - vmax);
        sum += v[c];
    }
#pragma unroll
    for (int off = 32; off; off >>= 1) sum += __shfl_xor(sum, off);
    if ((tid & 63) == 0) wred2[tid >> 6] = sum;
    __syncthreads();
    sum = wred2[0] + wred2[1] + wred2[2] + wred2[3];
    const float inv = 1.0f / sum;

    f32x4* o4 = (f32x4*)(attn + (long)row * NN);
    short4v* b4 = (short4v*)(attnB + (long)row * NN);
#pragma unroll
    for (int c = 0; c < 4; c++) {
        int idx = c * 256 + tid;
        f32x4 o;
        o.x = v[c * 4 + 0] * inv; o.y = v[c * 4 + 1] * inv;
        o.z = v[c * 4 + 2] * inv; o.w = v[c * 4 + 3] * inv;
        __builtin_nontemporal_store(o, &o4[idx]);
        short4v sb;
        sb.x = f2bf(o.x); sb.y = f2bf(o.y); sb.z = f2bf(o.z); sb.w = f2bf(o.w);
        b4[idx] = sb;
    }
}

// ---------------------------------------------------------------------------
// pool mean + classifier + 2-way softmax
// ---------------------------------------------------------------------------
__global__ __launch_bounds__(256) void k_final(const float* __restrict__ pool_acc,
                                               const float* __restrict__ clf_w,
                                               const float* __restrict__ clf_b,
                                               float* __restrict__ out_pool,
                                               float* __restrict__ out_label) {
    __shared__ float r0[4], r1[4];
    const int tid = threadIdx.x;
    float l0 = 0.f, l1 = 0.f;
#pragma unroll
    for (int q = 0; q < 4; q++) {
        int f = q * 256 + tid;
        float p = pool_acc[f] * (1.0f / NN);
        out_pool[f] = p;
        l0 += p * clf_w[f * 2 + 0];
        l1 += p * clf_w[f * 2 + 1];
    }
#pragma unroll
    for (int off = 32; off; off >>= 1) {
        l0 += __shfl_xor(l0, off);
        l1 += __shfl_xor(l1, off);
    }
    if ((tid & 63) == 0) { r0[tid >> 6] = l0; r1[tid >> 6] = l1; }
    __syncthreads();
    if (tid == 0) {
        float L0 = r0[0] + r0[1] + r0[2] + r0[3] + clf_b[0];
        float L1 = r1[0] + r1[1] + r1[2] + r1[3] + clf_b[1];
        float m = fmaxf(L0, L1);
        float e0 = __expf(L0 - m), e1 = __expf(L1 - m);
        float s = e0 + e1;
        out_label[0] = e0 / s;
        out_label[1] = e1 / s;
    }
}

// ---------------------------------------------------------------------------
extern "C" void kernel_launch(void* const* d_in, const int* in_sizes, int n_in,
                              void* d_out, int out_size, void* d_ws,
                              size_t ws_size, hipStream_t stream) {
    const int* inSen = (const int*)d_in[0];
    const int* adj = (const int*)d_in[1];
    const float* emb = (const float*)d_in[2];
    const float* W = (const float*)d_in[3];
    const float* a_src = (const float*)d_in[4];
    const float* a_dst = (const float*)d_in[5];
    const float* clf_w = (const float*)d_in[6];
    const float* clf_b = (const float*)d_in[7];

    float* out = (float*)d_out;
    float* out_pool = out;
    float* attn = out + 1024;
    float* sentence = out + 1024 + (long)NN * NN;
    float* out_label = out + 1024 + (long)NN * NN + (long)NN * WF;

    // ws layout:
    //   X     [NN][ED]    bf16   8 MB  @ 0
    //   Wt    [WF][ED]    bf16   2 MB  @ 8 MB
    //   Ht    [WF][NN]    bf16   8 MB  @ 10 MB
    //   attnB [NN][NN]    bf16  33.6MB @ 18 MB
    //   s_src/s_dst/pool (9216 f, zeroed in k_prep) @ 52 MB
    char* ws = (char*)d_ws;
    short* X = (short*)ws;
    short* Wt = (short*)(ws + (8l << 20));
    short* Ht = (short*)(ws + (10l << 20));
    short* attnB = (short*)(ws + (18l << 20));
    float* s_src = (float*)(ws + (52l << 20));
    float* s_dst = s_src + NN;
    float* pool = s_dst + NN;

    k_prep<<<256 + NN, 256, 0, stream>>>(W, Wt, inSen, emb, X, s_src);

    // GEMM1: Ht[f][i] = sum_k Wt[f][k] * X[i][k]
    // M=WF, N=NN, K=ED; BM=64, BN=128 -> 512 blocks, bf16 out + fused scores
    gemm_bt2<64, 128, 0, false><<<dim3(NN / 128, WF / 64, 1), 256, 0, stream>>>(
        Wt, X, NN, ED, ED, Ht, a_src, a_dst, s_src, s_dst, nullptr);

    k_attn<<<NN, 256, 0, stream>>>(adj, s_src, s_dst, attn, attnB);

    // GEMM2: sentence[i][f] = sum_k attnB[i][k] * Ht[f][k]
    // M=NN, N=WF, K=NN. BM=64, BN=128, no split-K -> 64x8 = 512 blocks
    // (2/CU), m-fast dispatch so 64-block groups share one Ht B-panel.
    // Direct fp32 stores (no memset, no RMW) + fused pool colsum.
    gemm_bt2<64, 128, 1, true><<<dim3(NN / 64, WF / 128, 1), 256, 0, stream>>>(
        attnB, Ht, WF, NN, NN, sentence,
        nullptr, nullptr, nullptr, nullptr, pool);

    k_final<<<1, 256, 0, stream>>>(pool, clf_w, clf_b, out_pool, out_label);
}

// Round 5
// 387.355 us; speedup vs baseline: 1.1210x; 1.0153x over previous
//
#include <hip/hip_runtime.h>
#include <hip/hip_bf16.h>

#define NN 4096      // nodes
#define ED 1024      // edim
#define WF 1024      // wfeat
#define SLOPEC 0.01f
#define NEG_INFC -1e9f

typedef __attribute__((ext_vector_type(8))) short bf16x8;
typedef __attribute__((ext_vector_type(4))) short short4v;
typedef __attribute__((ext_vector_type(4))) float f32x4;
typedef __attribute__((ext_vector_type(4))) int int4v;

__device__ __forceinline__ float bf2f(short s) {
    union { unsigned u; float f; } v;
    v.u = ((unsigned)(unsigned short)s) << 16;
    return v.f;
}
__device__ __forceinline__ short f2bf(float f) {
    unsigned u = __float_as_uint(f);
    unsigned r = u + 0x7FFFu + ((u >> 16) & 1u);   // RNE (finite data)
    return (short)(r >> 16);
}

typedef __attribute__((address_space(3))) unsigned lds_u32;
typedef const __attribute__((address_space(1))) unsigned gbl_u32;
__device__ __forceinline__ void g2l16(const short* g, short* l) {
    __builtin_amdgcn_global_load_lds((gbl_u32*)g, (lds_u32*)l, 16, 0, 0);
}

// ---------------------------------------------------------------------------
// Fused prep:
//  blocks [0,256): transpose+convert W [ED][WF] fp32 -> Wt [WF][ED] bf16
//    blocks [0,9) additionally zero s_src/s_dst/pool (9216 floats)
//  blocks [256,256+NN): gather+convert X[i][k] = bf16(emb[inSen[i]][k])
// ---------------------------------------------------------------------------
__global__ __launch_bounds__(256) void k_prep(const float* __restrict__ W,
                                              short* __restrict__ Wt,
                                              const int* __restrict__ inSen,
                                              const float* __restrict__ emb,
                                              short* __restrict__ X,
                                              float* __restrict__ zbase) {
    if (blockIdx.x < 256) {
        if (blockIdx.x < 9) {
            // zero s_src (NN) + s_dst (NN) + pool (WF) = 9216 floats
            f32x4 z = {0.f, 0.f, 0.f, 0.f};
            *(f32x4*)(zbase + blockIdx.x * 1024 + threadIdx.x * 4) = z;
        }
        __shared__ float t[64][65];
        const int n0 = (blockIdx.x & 15) * 64, k0 = (blockIdx.x >> 4) * 64;
        const int tx = threadIdx.x & 63, ty = threadIdx.x >> 6;
#pragma unroll
        for (int p = 0; p < 16; p++) {
            int r = p * 4 + ty;
            t[r][tx] = W[(long)(k0 + r) * WF + n0 + tx];
        }
        __syncthreads();
#pragma unroll
        for (int p = 0; p < 16; p++) {
            int r = p * 4 + ty;  // n index
            Wt[(long)(n0 + r) * ED + k0 + tx] = f2bf(t[tx][r]);
        }
    } else {
        const int row = blockIdx.x - 256;
        const int tid = threadIdx.x;
        const long idx = inSen[row];
        const float4 v = ((const float4*)(emb + idx * ED))[tid];
        short4v s;
        s.x = f2bf(v.x); s.y = f2bf(v.y); s.z = f2bf(v.z); s.w = f2bf(v.w);
        *(short4v*)(X + (long)row * ED + tid * 4) = s;
    }
}

// ---------------------------------------------------------------------------
// GEMM (m97 structure, BK=128): C[M][N] = A[M][K] * Bt[N][K], bf16 in.
// Tile BM x BN, 256 thr = 4 waves (2x2). global_load_lds width=16.
// BK=128 staged as four [rows][32] sub-chunks -> one barrier pair per 128-K
// (halves the vmcnt-drain count vs BK=64; occupancy unchanged at 2/CU since
// launch_bounds already caps it and LDS 48KB*2 = 96KB < 160KB).
// MFMA k-order preserved -> bit-identical accumulation.
// MODE 0: bf16 C store via LDS repack + fused s_src/s_dst column scores.
// MODE 1: direct fp32 C store + fused pool colsum (atomic on pool only).
// SWAPXY: blockIdx.x indexes M-tiles (m-fast dispatch -> B-panel L2 reuse).
// ---------------------------------------------------------------------------
template <int BM, int BN, int MODE, bool SWAPXY>
__global__ __launch_bounds__(256, 2) void gemm_bt2(
    const short* __restrict__ A, const short* __restrict__ Bt,
    int N, int K, int Kc, void* __restrict__ Cout,
    const float* __restrict__ a_src, const float* __restrict__ a_dst,
    float* __restrict__ s_src, float* __restrict__ s_dst,
    float* __restrict__ pool) {
    constexpr int TM = BM / 32;           // m-frags per wave
    constexpr int TN = BN / 32;           // n-frags per wave
    constexpr int STAGE = (BM + BN) * 128;              // BK=128
    constexpr int SMEMSZ = (MODE == 0 && BM * BN > STAGE) ? BM * BN : STAGE;
    __shared__ __align__(16) short smem[SMEMSZ];
    short* sA = smem;                 // [4][BM][32]
    short* sB = smem + BM * 128;      // [4][BN][32]

    const int tid = threadIdx.x;
    const int lane = tid & 63;
    const int wid = tid >> 6;
    const int wm = wid >> 1, wn = wid & 1;
    const int n0 = (SWAPXY ? blockIdx.y : blockIdx.x) * BN;
    const int m0 = (SWAPXY ? blockIdx.x : blockIdx.y) * BM;
    const int ks = blockIdx.z * Kc;

    const int srow = tid >> 2;        // 0..63
    const int sc8 = (tid & 3) * 8;    // 0,8,16,24
    const int l15 = lane & 15;
    const int lhi = lane >> 4;

    f32x4 acc[TM][TN];
#pragma unroll
    for (int t = 0; t < TM; t++)
#pragma unroll
        for (int u = 0; u < TN; u++) acc[t][u] = (f32x4){0.f, 0.f, 0.f, 0.f};

    const short* Ab = A + (long)(m0 + srow) * K + ks + sc8;
    const short* Bb = Bt + (long)(n0 + srow) * K + ks + sc8;
    const long rstep = (long)64 * K;   // 64 rows

    for (int k0 = 0; k0 < Kc; k0 += 128) {
#pragma unroll
        for (int c = 0; c < 4; c++) {
#pragma unroll
            for (int p = 0; p < BM / 64; p++)
                g2l16(Ab + p * rstep + k0 + c * 32,
                      sA + c * (BM * 32) + (p * 256 + wid * 64) * 8);
#pragma unroll
            for (int p = 0; p < BN / 64; p++)
                g2l16(Bb + p * rstep + k0 + c * 32,
                      sB + c * (BN * 32) + (p * 256 + wid * 64) * 8);
        }
        __syncthreads();   // drains vmcnt for global_load_lds (once per 128-K)

#pragma unroll
        for (int c = 0; c < 4; c++) {
            bf16x8 af[TM], bfr[TN];
#pragma unroll
            for (int t = 0; t < TM; t++)
                af[t] = *(const bf16x8*)&sA[c * (BM * 32) +
                        (wm * (BM / 2) + t * 16 + l15) * 32 + lhi * 8];
#pragma unroll
            for (int u = 0; u < TN; u++)
                bfr[u] = *(const bf16x8*)&sB[c * (BN * 32) +
                         (wn * (BN / 2) + u * 16 + l15) * 32 + lhi * 8];
#pragma unroll
            for (int t = 0; t < TM; t++)
#pragma unroll
                for (int u = 0; u < TN; u++)
                    acc[t][u] = __builtin_amdgcn_mfma_f32_16x16x32_bf16(
                        af[t], bfr[u], acc[t][u], 0, 0, 0);
        }
        __syncthreads();
    }

    // Epilogue. D mapping per 16x16 tile: col = l15, row = lhi*4 + r
    if (MODE == 0) {
        short* sT = smem;   // safe: last loop iteration ended with a barrier
#pragma unroll
        for (int t = 0; t < TM; t++)
#pragma unroll
            for (int u = 0; u < TN; u++)
#pragma unroll
                for (int r = 0; r < 4; r++) {
                    int m = wm * (BM / 2) + t * 16 + lhi * 4 + r;
                    int n = wn * (BN / 2) + u * 16 + l15;
                    sT[m * BN + n] = f2bf(acc[t][u][r]);
                }
        __syncthreads();
        short* C = (short*)Cout;
#pragma unroll
        for (int q = 0; q < BM * BN / 2048; q++) {
            int idx = q * 256 + tid;
            int row = idx / (BN / 8);
            int c8 = (idx % (BN / 8)) * 8;
            *(bf16x8*)(C + (long)(m0 + row) * N + n0 + c8) =
                *(const bf16x8*)&sT[row * BN + c8];
        }
        // s_src[n] += sum_m Ht[m][n]*a_src[m] over this block's m-range
        float ps[TN], pd[TN];
#pragma unroll
        for (int u = 0; u < TN; u++) { ps[u] = 0.f; pd[u] = 0.f; }
#pragma unroll
        for (int t = 0; t < TM; t++)
#pragma unroll
            for (int r = 0; r < 4; r++) {
                int m = m0 + wm * (BM / 2) + t * 16 + lhi * 4 + r;
                float as = a_src[m], ad = a_dst[m];
#pragma unroll
                for (int u = 0; u < TN; u++) {
                    ps[u] += acc[t][u][r] * as;
                    pd[u] += acc[t][u][r] * ad;
                }
            }
#pragma unroll
        for (int u = 0; u < TN; u++) {
            ps[u] += __shfl_xor(ps[u], 16); ps[u] += __shfl_xor(ps[u], 32);
            pd[u] += __shfl_xor(pd[u], 16); pd[u] += __shfl_xor(pd[u], 32);
        }
        if (lane < 16) {
#pragma unroll
            for (int u = 0; u < TN; u++) {
                int n = n0 + wn * (BN / 2) + u * 16 + lane;
                atomicAdd(s_src + n, ps[u]);
                atomicAdd(s_dst + n, pd[u]);
            }
        }
    } else {
        // MODE 1: direct fp32 store (no split-K, no RMW) + pool colsum.
        float* C = (float*)Cout;
        float pp[TN];
#pragma unroll
        for (int u = 0; u < TN; u++) pp[u] = 0.f;
#pragma unroll
        for (int t = 0; t < TM; t++)
#pragma unroll
            for (int u = 0; u < TN; u++)
#pragma unroll
                for (int r = 0; r < 4; r++) {
                    int m = wm * (BM / 2) + t * 16 + lhi * 4 + r;
                    int n = wn * (BN / 2) + u * 16 + l15;
                    C[(long)(m0 + m) * N + n0 + n] = acc[t][u][r];
                    pp[u] += acc[t][u][r];
                }
#pragma unroll
        for (int u = 0; u < TN; u++) {
            pp[u] += __shfl_xor(pp[u], 16);
            pp[u] += __shfl_xor(pp[u], 32);
        }
        if (lane < 16) {
#pragma unroll
            for (int u = 0; u < TN; u++) {
                int n = n0 + wn * (BN / 2) + u * 16 + lane;
                atomicAdd(pool + n, pp[u]);
            }
        }
    }
}

// ---------------------------------------------------------------------------
// Masked softmax row -> attn fp32 (d_out, NT) + attnB bf16 (ws, GEMM2 A)
// ---------------------------------------------------------------------------
__global__ __launch_bounds__(256) void k_attn(const int* __restrict__ adj,
                                              const float* __restrict__ s_src,
                                              const float* __restrict__ s_dst,
                                              float* __restrict__ attn,
                                              short* __restrict__ attnB) {
    __shared__ float wred[4];
    __shared__ float wred2[4];
    const int row = blockIdx.x;
    const int tid = threadIdx.x;
    const float ss = s_src[row];
    const int4v* adj4 = (const int4v*)(adj + (long)row * NN);
    const f32x4* sd4 = (const f32x4*)s_dst;
    float v[16];
    float vmax = -3e38f;
#pragma unroll
    for (int c = 0; c < 4; c++) {
        int idx = c * 256 + tid;
        int4v a = __builtin_nontemporal_load(&adj4[idx]);
        f32x4 d = sd4[idx];
        float x0 = ss + d.x; x0 = x0 > 0.f ? x0 : SLOPEC * x0; x0 = a.x > 0 ? x0 : NEG_INFC;
        float x1 = ss + d.y; x1 = x1 > 0.f ? x1 : SLOPEC * x1; x1 = a.y > 0 ? x1 : NEG_INFC;
        float x2 = ss + d.z; x2 = x2 > 0.f ? x2 : SLOPEC * x2; x2 = a.z > 0 ? x2 : NEG_INFC;
        float x3 = ss + d.w; x3 = x3 > 0.f ? x3 : SLOPEC * x3; x3 = a.w > 0 ? x3 : NEG_INFC;
        v[c * 4 + 0] = x0; v[c * 4 + 1] = x1; v[c * 4 + 2] = x2; v[c * 4 + 3] = x3;
        vmax = fmaxf(vmax, fmaxf(fmaxf(x0, x1), fmaxf(x2, x3)));
    }
#pragma unroll
    for (int off = 32; off; off >>= 1) vmax = fmaxf(vmax, __shfl_xor(vmax, off));
    if ((tid & 63) == 0) wred[tid >> 6] = vmax;
    __syncthreads();
    vmax = fmaxf(fmaxf(wred[0], wred[1]), fmaxf(wred[2], wred[3]));

    float sum = 0.f;
#pragma unroll
    for (int c = 0; c < 16; c++) {
        v[c] = __expf(v[c] - vmax);
        sum += v[c];
    }
#pragma unroll
    for (int off = 32; off; off >>= 1) sum += __shfl_xor(sum, off);
    if ((tid & 63) == 0) wred2[tid >> 6] = sum;
    __syncthreads();
    sum = wred2[0] + wred2[1] + wred2[2] + wred2[3];
    const float inv = 1.0f / sum;

    f32x4* o4 = (f32x4*)(attn + (long)row * NN);
    short4v* b4 = (short4v*)(attnB + (long)row * NN);
#pragma unroll
    for (int c = 0; c < 4; c++) {
        int idx = c * 256 + tid;
        f32x4 o;
        o.x = v[c * 4 + 0] * inv; o.y = v[c * 4 + 1] * inv;
        o.z = v[c * 4 + 2] * inv; o.w = v[c * 4 + 3] * inv;
        __builtin_nontemporal_store(o, &o4[idx]);
        short4v sb;
        sb.x = f2bf(o.x); sb.y = f2bf(o.y); sb.z = f2bf(o.z); sb.w = f2bf(o.w);
        b4[idx] = sb;
    }
}

// ---------------------------------------------------------------------------
// pool mean + classifier + 2-way softmax
// ---------------------------------------------------------------------------
__global__ __launch_bounds__(256) void k_final(const float* __restrict__ pool_acc,
                                               const float* __restrict__ clf_w,
                                               const float* __restrict__ clf_b,
                                               float* __restrict__ out_pool,
                                               float* __restrict__ out_label) {
    __shared__ float r0[4], r1[4];
    const int tid = threadIdx.x;
    float l0 = 0.f, l1 = 0.f;
#pragma unroll
    for (int q = 0; q < 4; q++) {
        int f = q * 256 + tid;
        float p = pool_acc[f] * (1.0f / NN);
        out_pool[f] = p;
        l0 += p * clf_w[f * 2 + 0];
        l1 += p * clf_w[f * 2 + 1];
    }
#pragma unroll
    for (int off = 32; off; off >>= 1) {
        l0 += __shfl_xor(l0, off);
        l1 += __shfl_xor(l1, off);
    }
    if ((tid & 63) == 0) { r0[tid >> 6] = l0; r1[tid >> 6] = l1; }
    __syncthreads();
    if (tid == 0) {
        float L0 = r0[0] + r0[1] + r0[2] + r0[3] + clf_b[0];
        float L1 = r1[0] + r1[1] + r1[2] + r1[3] + clf_b[1];
        float m = fmaxf(L0, L1);
        float e0 = __expf(L0 - m), e1 = __expf(L1 - m);
        float s = e0 + e1;
        out_label[0] = e0 / s;
        out_label[1] = e1 / s;
    }
}

// ---------------------------------------------------------------------------
extern "C" void kernel_launch(void* const* d_in, const int* in_sizes, int n_in,
                              void* d_out, int out_size, void* d_ws,
                              size_t ws_size, hipStream_t stream) {
    const int* inSen = (const int*)d_in[0];
    const int* adj = (const int*)d_in[1];
    const float* emb = (const float*)d_in[2];
    const float* W = (const float*)d_in[3];
    const float* a_src = (const float*)d_in[4];
    const float* a_dst = (const float*)d_in[5];
    const float* clf_w = (const float*)d_in[6];
    const float* clf_b = (const float*)d_in[7];

    float* out = (float*)d_out;
    float* out_pool = out;
    float* attn = out + 1024;
    float* sentence = out + 1024 + (long)NN * NN;
    float* out_label = out + 1024 + (long)NN * NN + (long)NN * WF;

    // ws layout:
    //   X     [NN][ED]    bf16   8 MB  @ 0
    //   Wt    [WF][ED]    bf16   2 MB  @ 8 MB
    //   Ht    [WF][NN]    bf16   8 MB  @ 10 MB
    //   attnB [NN][NN]    bf16  33.6MB @ 18 MB
    //   s_src/s_dst/pool (9216 f, zeroed in k_prep) @ 52 MB
    char* ws = (char*)d_ws;
    short* X = (short*)ws;
    short* Wt = (short*)(ws + (8l << 20));
    short* Ht = (short*)(ws + (10l << 20));
    short* attnB = (short*)(ws + (18l << 20));
    float* s_src = (float*)(ws + (52l << 20));
    float* s_dst = s_src + NN;
    float* pool = s_dst + NN;

    k_prep<<<256 + NN, 256, 0, stream>>>(W, Wt, inSen, emb, X, s_src);

    // GEMM1: Ht[f][i] = sum_k Wt[f][k] * X[i][k]
    // M=WF, N=NN, K=ED; BM=64, BN=128 -> 512 blocks, bf16 out + fused scores
    gemm_bt2<64, 128, 0, false><<<dim3(NN / 128, WF / 64, 1), 256, 0, stream>>>(
        Wt, X, NN, ED, ED, Ht, a_src, a_dst, s_src, s_dst, nullptr);

    k_attn<<<NN, 256, 0, stream>>>(adj, s_src, s_dst, attn, attnB);

    // GEMM2: sentence[i][f] = sum_k attnB[i][k] * Ht[f][k]
    // M=NN, N=WF, K=NN. BM=64, BN=128, no split-K -> 64x8 = 512 blocks
    // (2/CU), m-fast dispatch so 64-block groups share one Ht B-panel.
    // Direct fp32 stores (no memset, no RMW) + fused pool colsum.
    gemm_bt2<64, 128, 1, true><<<dim3(NN / 64, WF / 128, 1), 256, 0, stream>>>(
        attnB, Ht, WF, NN, NN, sentence,
        nullptr, nullptr, nullptr, nullptr, pool);

    k_final<<<1, 256, 0, stream>>>(pool, clf_w, clf_b, out_pool, out_label);
}